// Round 1
// baseline (5702.810 us; speedup 1.0000x reference)
//
#include <hip/hip_runtime.h>

#define N_NODES 50000
#define N_EDGES 1600000
#define D_FEAT 512
#define FILTERS 256
#define NUM_CLASSES 16

// ---------------------------------------------------------------------------
// GEMM1: XW1[M,N] = X[M,K] @ W1[K,N], M=50000, K=512, N=256, fp32 vector ALU.
// 64x64 tile, BK=16, 256 threads, 4x4 microtile per thread.
// ---------------------------------------------------------------------------
__global__ __launch_bounds__(256) void gemm1_kernel(
    const float* __restrict__ A, const float* __restrict__ B,
    float* __restrict__ C) {
  const int M = N_NODES, N = FILTERS, K = D_FEAT;
  __shared__ float As[16][68];  // [k][m], padded 64->68 to dodge bank conflicts
  __shared__ float Bs[16][64];  // [k][n]

  const int tid = threadIdx.x;
  const int tx = tid & 15;       // n direction
  const int ty = tid >> 4;       // m direction
  const int m0 = blockIdx.y * 64;
  const int n0 = blockIdx.x * 64;

  // load mapping
  const int arow = tid >> 2;        // 0..63  (m within tile)
  const int acol = (tid & 3) * 4;   // 0,4,8,12 (k within tile)
  const int brow = tid >> 4;        // 0..15 (k within tile)
  const int bcol = (tid & 15) * 4;  // 0..60 (n within tile)

  float acc[4][4] = {};

  for (int k0 = 0; k0 < K; k0 += 16) {
    float4 av = make_float4(0.f, 0.f, 0.f, 0.f);
    if (m0 + arow < M)
      av = *(const float4*)(A + (size_t)(m0 + arow) * K + k0 + acol);
    As[acol + 0][arow] = av.x;
    As[acol + 1][arow] = av.y;
    As[acol + 2][arow] = av.z;
    As[acol + 3][arow] = av.w;

    float4 bv = *(const float4*)(B + (size_t)(k0 + brow) * N + n0 + bcol);
    *(float4*)&Bs[brow][bcol] = bv;

    __syncthreads();

#pragma unroll
    for (int k = 0; k < 16; ++k) {
      float4 a4 = *(const float4*)&As[k][ty * 4];
      float4 b4 = *(const float4*)&Bs[k][tx * 4];
      float a[4] = {a4.x, a4.y, a4.z, a4.w};
      float b[4] = {b4.x, b4.y, b4.z, b4.w};
#pragma unroll
      for (int i = 0; i < 4; ++i)
#pragma unroll
        for (int j = 0; j < 4; ++j) acc[i][j] = fmaf(a[i], b[j], acc[i][j]);
    }
    __syncthreads();
  }

#pragma unroll
  for (int i = 0; i < 4; ++i) {
    int m = m0 + ty * 4 + i;
    if (m < M) {
      *(float4*)(C + (size_t)m * N + n0 + tx * 4) =
          make_float4(acc[i][0], acc[i][1], acc[i][2], acc[i][3]);
    }
  }
}

// ---------------------------------------------------------------------------
// Scatter1: h1[dst] += w * xw1[src]  over 256 features. One wave per edge,
// each lane owns 4 consecutive features (float4 read, 4 atomics).
// ---------------------------------------------------------------------------
__global__ __launch_bounds__(256) void scatter1_kernel(
    const float* __restrict__ xw1, const float* __restrict__ ew,
    const int* __restrict__ esrc, const int* __restrict__ edst,
    float* __restrict__ h1) {
  const int e = blockIdx.x * 4 + (threadIdx.x >> 6);
  if (e >= N_EDGES) return;
  const int lane = threadIdx.x & 63;
  const int s = esrc[e];
  const int d = edst[e];
  const float w = ew[e];
  const float4 v = ((const float4*)(xw1 + (size_t)s * FILTERS))[lane];
  float* o = h1 + (size_t)d * FILTERS + lane * 4;
  atomicAdd(o + 0, w * v.x);
  atomicAdd(o + 1, w * v.y);
  atomicAdd(o + 2, w * v.z);
  atomicAdd(o + 3, w * v.w);
}

// ---------------------------------------------------------------------------
// GEMM2: H2[M,16] = relu(H1[M,256]) @ W2[256,16]. W2 staged in LDS.
// 256 threads = 64 rows x 4 class-groups (4 classes each).
// ---------------------------------------------------------------------------
__global__ __launch_bounds__(256) void gemm2_kernel(
    const float* __restrict__ H1, const float* __restrict__ W2,
    float* __restrict__ H2) {
  __shared__ float w2s[FILTERS * NUM_CLASSES];  // 16 KiB
  const int tid = threadIdx.x;
  for (int i = tid; i < FILTERS * NUM_CLASSES; i += 256) w2s[i] = W2[i];
  __syncthreads();

  const int row = blockIdx.x * 64 + (tid >> 2);
  if (row >= N_NODES) return;
  const int cg = (tid & 3) * 4;

  const float4* hrow = (const float4*)(H1 + (size_t)row * FILTERS);
  float acc[4] = {0.f, 0.f, 0.f, 0.f};
  for (int k4 = 0; k4 < FILTERS / 4; ++k4) {
    float4 hv = hrow[k4];
    float h[4] = {hv.x, hv.y, hv.z, hv.w};
#pragma unroll
    for (int j = 0; j < 4; ++j) {
      float hh = fmaxf(h[j], 0.f);
      const float* wrow = &w2s[(k4 * 4 + j) * NUM_CLASSES + cg];
#pragma unroll
      for (int c = 0; c < 4; ++c) acc[c] = fmaf(hh, wrow[c], acc[c]);
    }
  }
  *(float4*)(H2 + (size_t)row * NUM_CLASSES + cg) =
      make_float4(acc[0], acc[1], acc[2], acc[3]);
}

// ---------------------------------------------------------------------------
// Scatter2: logits[dst] += w * h2[src] over 16 classes. 16 threads/edge.
// ---------------------------------------------------------------------------
__global__ __launch_bounds__(256) void scatter2_kernel(
    const float* __restrict__ h2, const float* __restrict__ ew,
    const int* __restrict__ esrc, const int* __restrict__ edst,
    float* __restrict__ logits) {
  const long long idx = (long long)blockIdx.x * 256 + threadIdx.x;
  const int e = (int)(idx >> 4);
  if (e >= N_EDGES) return;
  const int c = (int)(idx & 15);
  const int s = esrc[e];
  const int d = edst[e];
  const float w = ew[e];
  atomicAdd(logits + (size_t)d * NUM_CLASSES + c,
            w * h2[(size_t)s * NUM_CLASSES + c]);
}

// ---------------------------------------------------------------------------
// Softmax over 16 classes, in place on d_out.
// ---------------------------------------------------------------------------
__global__ __launch_bounds__(256) void softmax_kernel(float* __restrict__ io) {
  const int n = blockIdx.x * 256 + threadIdx.x;
  if (n >= N_NODES) return;
  float4* p = (float4*)(io + (size_t)n * NUM_CLASSES);
  float4 r[4] = {p[0], p[1], p[2], p[3]};
  float* v = (float*)r;
  float m = v[0];
#pragma unroll
  for (int i = 1; i < 16; ++i) m = fmaxf(m, v[i]);
  float s = 0.f;
#pragma unroll
  for (int i = 0; i < 16; ++i) {
    v[i] = __expf(v[i] - m);
    s += v[i];
  }
  const float inv = 1.f / s;
#pragma unroll
  for (int i = 0; i < 16; ++i) v[i] *= inv;
  p[0] = r[0];
  p[1] = r[1];
  p[2] = r[2];
  p[3] = r[3];
}

extern "C" void kernel_launch(void* const* d_in, const int* in_sizes, int n_in,
                              void* d_out, int out_size, void* d_ws,
                              size_t ws_size, hipStream_t stream) {
  const float* x = (const float*)d_in[0];     // [50000, 512]
  const float* W1 = (const float*)d_in[1];    // [512, 256]
  const float* W2 = (const float*)d_in[2];    // [256, 16]
  const float* ew = (const float*)d_in[3];    // [E]
  const int* esrc = (const int*)d_in[4];      // [E]
  const int* edst = (const int*)d_in[5];      // [E]
  float* out = (float*)d_out;                 // [50000, 16]

  float* xw1 = (float*)d_ws;                        // 50000*256
  float* h1 = xw1 + (size_t)N_NODES * FILTERS;      // 50000*256
  float* h2 = h1 + (size_t)N_NODES * FILTERS;       // 50000*16

  // zero accumulation buffers
  hipMemsetAsync(h1, 0, (size_t)N_NODES * FILTERS * sizeof(float), stream);
  hipMemsetAsync(out, 0, (size_t)N_NODES * NUM_CLASSES * sizeof(float), stream);

  // Layer 1: XW1 = X @ W1
  dim3 g1(FILTERS / 64, (N_NODES + 63) / 64);
  gemm1_kernel<<<g1, 256, 0, stream>>>(x, W1, xw1);

  // h1[dst] += w * xw1[src]
  scatter1_kernel<<<(N_EDGES + 3) / 4, 256, 0, stream>>>(xw1, ew, esrc, edst,
                                                         h1);

  // H2 = relu(h1) @ W2
  gemm2_kernel<<<(N_NODES + 63) / 64, 256, 0, stream>>>(h1, W2, h2);

  // logits[dst] += w * h2[src]   (accumulate directly into d_out)
  scatter2_kernel<<<(N_EDGES * 16 + 255) / 256, 256, 0, stream>>>(h2, ew, esrc,
                                                                  edst, out);

  // softmax in place
  softmax_kernel<<<(N_NODES + 255) / 256, 256, 0, stream>>>(out);
}

// Round 2
// 798.657 us; speedup vs baseline: 7.1405x; 7.1405x over previous
//
#include <hip/hip_runtime.h>

#define N_NODES 50000
#define N_EDGES 1600000
#define D_FEAT 512
#define FILTERS 256
#define NUM_CLASSES 16

// ---------------------------------------------------------------------------
// GEMM1: XW1[M,N] = X[M,K] @ W1[K,N], M=50000, K=512, N=256, fp32 vector ALU.
// 64x64 tile, BK=16, 256 threads, 4x4 microtile per thread.
// ---------------------------------------------------------------------------
__global__ __launch_bounds__(256) void gemm1_kernel(
    const float* __restrict__ A, const float* __restrict__ B,
    float* __restrict__ C) {
  const int M = N_NODES, N = FILTERS, K = D_FEAT;
  __shared__ float As[16][68];  // [k][m], padded
  __shared__ float Bs[16][64];  // [k][n]

  const int tid = threadIdx.x;
  const int tx = tid & 15;       // n direction
  const int ty = tid >> 4;       // m direction
  const int m0 = blockIdx.y * 64;
  const int n0 = blockIdx.x * 64;

  const int arow = tid >> 2;
  const int acol = (tid & 3) * 4;
  const int brow = tid >> 4;
  const int bcol = (tid & 15) * 4;

  float acc[4][4] = {};

  for (int k0 = 0; k0 < K; k0 += 16) {
    float4 av = make_float4(0.f, 0.f, 0.f, 0.f);
    if (m0 + arow < M)
      av = *(const float4*)(A + (size_t)(m0 + arow) * K + k0 + acol);
    As[acol + 0][arow] = av.x;
    As[acol + 1][arow] = av.y;
    As[acol + 2][arow] = av.z;
    As[acol + 3][arow] = av.w;

    float4 bv = *(const float4*)(B + (size_t)(k0 + brow) * N + n0 + bcol);
    *(float4*)&Bs[brow][bcol] = bv;

    __syncthreads();

#pragma unroll
    for (int k = 0; k < 16; ++k) {
      float4 a4 = *(const float4*)&As[k][ty * 4];
      float4 b4 = *(const float4*)&Bs[k][tx * 4];
      float a[4] = {a4.x, a4.y, a4.z, a4.w};
      float b[4] = {b4.x, b4.y, b4.z, b4.w};
#pragma unroll
      for (int i = 0; i < 4; ++i)
#pragma unroll
        for (int j = 0; j < 4; ++j) acc[i][j] = fmaf(a[i], b[j], acc[i][j]);
    }
    __syncthreads();
  }

#pragma unroll
  for (int i = 0; i < 4; ++i) {
    int m = m0 + ty * 4 + i;
    if (m < M) {
      *(float4*)(C + (size_t)m * N + n0 + tx * 4) =
          make_float4(acc[i][0], acc[i][1], acc[i][2], acc[i][3]);
    }
  }
}

// ---------------------------------------------------------------------------
// CSR build: histogram of dst degrees
// ---------------------------------------------------------------------------
__global__ __launch_bounds__(256) void hist_kernel(const int* __restrict__ edst,
                                                   int* __restrict__ deg) {
  const int e = blockIdx.x * 256 + threadIdx.x;
  if (e < N_EDGES) atomicAdd(&deg[edst[e]], 1);
}

// ---------------------------------------------------------------------------
// Exclusive scan of deg[50000] -> row_ptr, cursor. Single block, 1024 thr,
// 8 elems/thread per chunk (chunk = 8192).
// ---------------------------------------------------------------------------
#define SCAN_THREADS 1024
#define SCAN_PT 8
__global__ __launch_bounds__(SCAN_THREADS) void scan_kernel(
    const int* __restrict__ deg, int* __restrict__ row_ptr,
    int* __restrict__ cursor) {
  __shared__ int sums[SCAN_THREADS];
  __shared__ int s_carry;
  if (threadIdx.x == 0) s_carry = 0;
  __syncthreads();
  const int chunk = SCAN_THREADS * SCAN_PT;
  for (int base = 0; base < N_NODES; base += chunk) {
    const int idx0 = base + threadIdx.x * SCAN_PT;
    int v[SCAN_PT];
    int local = 0;
#pragma unroll
    for (int i = 0; i < SCAN_PT; ++i) {
      int idx = idx0 + i;
      int d = (idx < N_NODES) ? deg[idx] : 0;
      v[i] = local;
      local += d;
    }
    sums[threadIdx.x] = local;
    __syncthreads();
    for (int off = 1; off < SCAN_THREADS; off <<= 1) {
      int t = (threadIdx.x >= off) ? sums[threadIdx.x - off] : 0;
      __syncthreads();
      sums[threadIdx.x] += t;
      __syncthreads();
    }
    const int thread_prefix = (threadIdx.x > 0) ? sums[threadIdx.x - 1] : 0;
    const int chunk_total = sums[SCAN_THREADS - 1];
    const int carry = s_carry;
#pragma unroll
    for (int i = 0; i < SCAN_PT; ++i) {
      int idx = idx0 + i;
      if (idx < N_NODES) {
        int ex = carry + thread_prefix + v[i];
        row_ptr[idx] = ex;
        cursor[idx] = ex;
      }
    }
    __syncthreads();
    if (threadIdx.x == 0) s_carry = carry + chunk_total;
    __syncthreads();
  }
  if (threadIdx.x == 0) row_ptr[N_NODES] = N_EDGES;
}

// ---------------------------------------------------------------------------
// Fill: permute edges into dst-sorted order, packing (src, weight_bits).
// ---------------------------------------------------------------------------
__global__ __launch_bounds__(256) void fill_kernel(
    const int* __restrict__ esrc, const int* __restrict__ edst,
    const float* __restrict__ ew, int* __restrict__ cursor,
    int2* __restrict__ meta) {
  const int e = blockIdx.x * 256 + threadIdx.x;
  if (e >= N_EDGES) return;
  const int d = edst[e];
  const int pos = atomicAdd(&cursor[d], 1);
  meta[pos] = make_int2(esrc[e], __float_as_int(ew[e]));
}

// ---------------------------------------------------------------------------
// Gather1: h1[n] = sum_{e in CSR row n} w_e * xw1[src_e].  One wave per node,
// lane owns 4 consecutive features (float4). No atomics.
// ---------------------------------------------------------------------------
__global__ __launch_bounds__(256) void gather1_kernel(
    const float* __restrict__ xw1, const int* __restrict__ row_ptr,
    const int2* __restrict__ meta, float* __restrict__ h1) {
  const int node = blockIdx.x * 4 + (threadIdx.x >> 6);
  const int lane = threadIdx.x & 63;
  const int beg = row_ptr[node];
  const int end = row_ptr[node + 1];
  float4 acc = make_float4(0.f, 0.f, 0.f, 0.f);
  for (int j = beg; j < end; ++j) {
    const int2 m = meta[j];
    const float w = __int_as_float(m.y);
    const float4 v = ((const float4*)(xw1 + (size_t)m.x * FILTERS))[lane];
    acc.x = fmaf(w, v.x, acc.x);
    acc.y = fmaf(w, v.y, acc.y);
    acc.z = fmaf(w, v.z, acc.z);
    acc.w = fmaf(w, v.w, acc.w);
  }
  ((float4*)(h1 + (size_t)node * FILTERS))[lane] = acc;
}

// ---------------------------------------------------------------------------
// GEMM2: H2[M,16] = relu(H1[M,256]) @ W2[256,16]. W2 staged in LDS.
// ---------------------------------------------------------------------------
__global__ __launch_bounds__(256) void gemm2_kernel(
    const float* __restrict__ H1, const float* __restrict__ W2,
    float* __restrict__ H2) {
  __shared__ float w2s[FILTERS * NUM_CLASSES];  // 16 KiB
  const int tid = threadIdx.x;
  for (int i = tid; i < FILTERS * NUM_CLASSES; i += 256) w2s[i] = W2[i];
  __syncthreads();

  const int row = blockIdx.x * 64 + (tid >> 2);
  if (row >= N_NODES) return;
  const int cg = (tid & 3) * 4;

  const float4* hrow = (const float4*)(H1 + (size_t)row * FILTERS);
  float acc[4] = {0.f, 0.f, 0.f, 0.f};
  for (int k4 = 0; k4 < FILTERS / 4; ++k4) {
    float4 hv = hrow[k4];
    float h[4] = {hv.x, hv.y, hv.z, hv.w};
#pragma unroll
    for (int j = 0; j < 4; ++j) {
      float hh = fmaxf(h[j], 0.f);
      const float* wrow = &w2s[(k4 * 4 + j) * NUM_CLASSES + cg];
#pragma unroll
      for (int c = 0; c < 4; ++c) acc[c] = fmaf(hh, wrow[c], acc[c]);
    }
  }
  *(float4*)(H2 + (size_t)row * NUM_CLASSES + cg) =
      make_float4(acc[0], acc[1], acc[2], acc[3]);
}

// ---------------------------------------------------------------------------
// Gather2 + softmax fused: logits[n][c] = sum w_e * h2[src_e][c], then
// softmax over the 16 classes held by a 16-lane group. No atomics.
// ---------------------------------------------------------------------------
__global__ __launch_bounds__(256) void gather2_softmax_kernel(
    const float* __restrict__ h2, const int* __restrict__ row_ptr,
    const int2* __restrict__ meta, float* __restrict__ out) {
  const int g = threadIdx.x >> 4;    // 16 groups per block
  const int c = threadIdx.x & 15;    // class
  const int node = blockIdx.x * 16 + g;
  const int beg = row_ptr[node];
  const int end = row_ptr[node + 1];
  float acc = 0.f;
  for (int j = beg; j < end; ++j) {
    const int2 m = meta[j];
    acc = fmaf(__int_as_float(m.y), h2[(size_t)m.x * NUM_CLASSES + c], acc);
  }
  float mx = acc;
#pragma unroll
  for (int off = 8; off >= 1; off >>= 1)
    mx = fmaxf(mx, __shfl_xor(mx, off, 16));
  const float e = __expf(acc - mx);
  float s = e;
#pragma unroll
  for (int off = 8; off >= 1; off >>= 1) s += __shfl_xor(s, off, 16);
  out[(size_t)node * NUM_CLASSES + c] = e / s;
}

extern "C" void kernel_launch(void* const* d_in, const int* in_sizes, int n_in,
                              void* d_out, int out_size, void* d_ws,
                              size_t ws_size, hipStream_t stream) {
  const float* x = (const float*)d_in[0];     // [50000, 512]
  const float* W1 = (const float*)d_in[1];    // [512, 256]
  const float* W2 = (const float*)d_in[2];    // [256, 16]
  const float* ew = (const float*)d_in[3];    // [E]
  const int* esrc = (const int*)d_in[4];      // [E]
  const int* edst = (const int*)d_in[5];      // [E]
  float* out = (float*)d_out;                 // [50000, 16]

  // workspace layout
  float* xw1 = (float*)d_ws;                            // 12.8M f32
  float* h1 = xw1 + (size_t)N_NODES * FILTERS;          // 12.8M f32
  float* h2 = h1 + (size_t)N_NODES * FILTERS;           // 0.8M f32
  int* row_ptr = (int*)(h2 + (size_t)N_NODES * NUM_CLASSES);  // 50001
  int* cursor = row_ptr + (N_NODES + 1);                // 50000
  int* deg = cursor + N_NODES;                          // 50000
  // pad to 8B for int2
  int2* meta = (int2*)(((uintptr_t)(deg + N_NODES) + 15) & ~(uintptr_t)15);

  // --- CSR build (dst-sorted) ---
  hipMemsetAsync(deg, 0, N_NODES * sizeof(int), stream);
  hist_kernel<<<(N_EDGES + 255) / 256, 256, 0, stream>>>(edst, deg);
  scan_kernel<<<1, SCAN_THREADS, 0, stream>>>(deg, row_ptr, cursor);
  fill_kernel<<<(N_EDGES + 255) / 256, 256, 0, stream>>>(esrc, edst, ew,
                                                         cursor, meta);

  // --- Layer 1 ---
  dim3 g1(FILTERS / 64, (N_NODES + 63) / 64);
  gemm1_kernel<<<g1, 256, 0, stream>>>(x, W1, xw1);
  gather1_kernel<<<N_NODES / 4, 256, 0, stream>>>(xw1, row_ptr, meta, h1);

  // --- Layer 2 ---
  gemm2_kernel<<<(N_NODES + 63) / 64, 256, 0, stream>>>(h1, W2, h2);
  gather2_softmax_kernel<<<N_NODES / 16, 256, 0, stream>>>(h2, row_ptr, meta,
                                                           out);
}

// Round 3
// 675.231 us; speedup vs baseline: 8.4457x; 1.1828x over previous
//
#include <hip/hip_runtime.h>

#define N_NODES 50000
#define N_EDGES 1600000
#define D_FEAT 512
#define FILTERS 256
#define NUM_CLASSES 16

typedef __bf16 bf16x8 __attribute__((ext_vector_type(8)));
typedef float f32x4 __attribute__((ext_vector_type(4)));

#define GLOAD_LDS16(g, l)                                                  \
  __builtin_amdgcn_global_load_lds(                                        \
      (const __attribute__((address_space(1))) unsigned int*)(g),          \
      (__attribute__((address_space(3))) unsigned int*)(l), 16, 0, 0)

// ---------------------------------------------------------------------------
// Split W1 [512,256] fp32 -> W1^T hi/lo bf16 [256,512]
// ---------------------------------------------------------------------------
__global__ __launch_bounds__(256) void split_w1_kernel(
    const float* __restrict__ W1, __bf16* __restrict__ Wth,
    __bf16* __restrict__ Wtl) {
  const int idx = blockIdx.x * 256 + threadIdx.x;  // 131072 total
  const int k = idx >> 8;
  const int n = idx & 255;
  const float v = W1[idx];
  const __bf16 h = (__bf16)v;
  const __bf16 l = (__bf16)(v - (float)h);
  Wth[n * D_FEAT + k] = h;
  Wtl[n * D_FEAT + k] = l;
}

// ---------------------------------------------------------------------------
// GEMM1 via MFMA bf16x3: C[M,256] = X[M,512] @ W1.  fp32-accurate.
// 128x128 tile, BK=32, 4 waves in 2x2, each wave 4x4 MFMA tiles of 16x16.
// A (X) converted fp32->bf16 hi/lo in-kernel; B staged via global_load_lds.
// ---------------------------------------------------------------------------
__global__ __launch_bounds__(256) void gemm1_mfma_kernel(
    const float* __restrict__ A,    // [M,512] fp32
    const __bf16* __restrict__ Bh,  // [256,512] W1^T hi
    const __bf16* __restrict__ Bl,  // [256,512] W1^T lo
    float* __restrict__ C) {        // [M,256]
  const int K = D_FEAT;
  __shared__ __bf16 sAh[128 * 32];
  __shared__ __bf16 sAl[128 * 32];
  __shared__ __bf16 sBh[128 * 32];
  __shared__ __bf16 sBl[128 * 32];

  const int tid = threadIdx.x;
  const int wave = tid >> 6;
  const int lane = tid & 63;
  const int wm = (wave >> 1) * 64;
  const int wn = (wave & 1) * 64;
  const int m0 = blockIdx.x * 128;
  const int n0 = blockIdx.y * 128;

  // A fp32 staging map: thread -> (row 0..127, 16 consecutive k)
  const int arow = tid >> 1;
  const int aks = (tid & 1) * 16;
  int am = m0 + arow;
  if (am >= N_NODES) am = N_NODES - 1;
  const float* aptr = A + (size_t)am * K + aks;

  // B global_load_lds map: lane -> (row lr of 16-row group, 16B chunk lc)
  const int lr = lane >> 2;
  const int lc = (lane & 3) * 8;
  // fragment map
  const int fm = lane & 15;
  const int fq = lane >> 4;

  f32x4 acc[4][4] = {};

  for (int k0 = 0; k0 < K; k0 += 32) {
    // A global loads into regs (can overlap prev compute)
    const float4* ap = (const float4*)(aptr + k0);
    const float4 a0 = ap[0], a1 = ap[1], a2 = ap[2], a3 = ap[3];

    __syncthreads();  // all waves done reading LDS from prev iter

    // B hi/lo staging direct to LDS (wave-uniform LDS base + lane*16)
#pragma unroll
    for (int i = 0; i < 2; ++i) {
      const int row = wave * 32 + i * 16;
      GLOAD_LDS16(Bh + (size_t)(n0 + row + lr) * K + k0 + lc,
                  sBh + row * 32);
      GLOAD_LDS16(Bl + (size_t)(n0 + row + lr) * K + k0 + lc,
                  sBl + row * 32);
    }

    // A convert fp32 -> bf16 hi/lo, write to LDS
    float va[16] = {a0.x, a0.y, a0.z, a0.w, a1.x, a1.y, a1.z, a1.w,
                    a2.x, a2.y, a2.z, a2.w, a3.x, a3.y, a3.z, a3.w};
    __bf16 hh[16], ll[16];
#pragma unroll
    for (int i = 0; i < 16; ++i) {
      const __bf16 h = (__bf16)va[i];
      hh[i] = h;
      ll[i] = (__bf16)(va[i] - (float)h);
    }
    *(bf16x8*)(sAh + arow * 32 + aks) = *(bf16x8*)&hh[0];
    *(bf16x8*)(sAh + arow * 32 + aks + 8) = *(bf16x8*)&hh[8];
    *(bf16x8*)(sAl + arow * 32 + aks) = *(bf16x8*)&ll[0];
    *(bf16x8*)(sAl + arow * 32 + aks + 8) = *(bf16x8*)&ll[8];

    __syncthreads();  // staging visible (drains vmcnt + lgkmcnt)

    bf16x8 fah[4], fal[4], fbh[4], fbl[4];
#pragma unroll
    for (int t = 0; t < 4; ++t) {
      const int moff = (wm + t * 16 + fm) * 32 + fq * 8;
      fah[t] = *(const bf16x8*)(sAh + moff);
      fal[t] = *(const bf16x8*)(sAl + moff);
      const int noff = (wn + t * 16 + fm) * 32 + fq * 8;
      fbh[t] = *(const bf16x8*)(sBh + noff);
      fbl[t] = *(const bf16x8*)(sBl + noff);
    }
#pragma unroll
    for (int i = 0; i < 4; ++i)
#pragma unroll
      for (int j = 0; j < 4; ++j)
        acc[i][j] = __builtin_amdgcn_mfma_f32_16x16x32_bf16(fah[i], fbh[j],
                                                            acc[i][j], 0, 0, 0);
#pragma unroll
    for (int i = 0; i < 4; ++i)
#pragma unroll
      for (int j = 0; j < 4; ++j)
        acc[i][j] = __builtin_amdgcn_mfma_f32_16x16x32_bf16(fah[i], fbl[j],
                                                            acc[i][j], 0, 0, 0);
#pragma unroll
    for (int i = 0; i < 4; ++i)
#pragma unroll
      for (int j = 0; j < 4; ++j)
        acc[i][j] = __builtin_amdgcn_mfma_f32_16x16x32_bf16(fal[i], fbh[j],
                                                            acc[i][j], 0, 0, 0);
  }

  // epilogue: D row = wm+ti*16+fq*4+r, col = wn+tj*16+fm
#pragma unroll
  for (int ti = 0; ti < 4; ++ti) {
#pragma unroll
    for (int r = 0; r < 4; ++r) {
      const int m = m0 + wm + ti * 16 + fq * 4 + r;
      if (m < N_NODES) {
#pragma unroll
        for (int tj = 0; tj < 4; ++tj) {
          const int n = n0 + wn + tj * 16 + fm;
          C[(size_t)m * FILTERS + n] = acc[ti][tj][r];
        }
      }
    }
  }
}

// ---------------------------------------------------------------------------
// CSR build: histogram of dst degrees
// ---------------------------------------------------------------------------
__global__ __launch_bounds__(256) void hist_kernel(const int* __restrict__ edst,
                                                   int* __restrict__ deg) {
  const int e = blockIdx.x * 256 + threadIdx.x;
  if (e < N_EDGES) atomicAdd(&deg[edst[e]], 1);
}

// ---------------------------------------------------------------------------
// Parallel exclusive scan: per-block scan -> scan block sums -> add offsets
// ---------------------------------------------------------------------------
#define SCAN_NB 196  // ceil(50000/256)
__global__ __launch_bounds__(256) void scan_blocks_kernel(
    const int* __restrict__ deg, int* __restrict__ row_ptr,
    int* __restrict__ bsum) {
  __shared__ int s[256];
  const int i = blockIdx.x * 256 + threadIdx.x;
  const int v = (i < N_NODES) ? deg[i] : 0;
  s[threadIdx.x] = v;
  __syncthreads();
  for (int off = 1; off < 256; off <<= 1) {
    const int t = (threadIdx.x >= off) ? s[threadIdx.x - off] : 0;
    __syncthreads();
    s[threadIdx.x] += t;
    __syncthreads();
  }
  if (i < N_NODES) row_ptr[i] = s[threadIdx.x] - v;  // block-local exclusive
  if (threadIdx.x == 255) bsum[blockIdx.x] = s[255];
}

__global__ __launch_bounds__(256) void scan_sums_kernel(int* __restrict__ bsum) {
  __shared__ int s[256];
  const int v = (threadIdx.x < SCAN_NB) ? bsum[threadIdx.x] : 0;
  s[threadIdx.x] = v;
  __syncthreads();
  for (int off = 1; off < 256; off <<= 1) {
    const int t = (threadIdx.x >= off) ? s[threadIdx.x - off] : 0;
    __syncthreads();
    s[threadIdx.x] += t;
    __syncthreads();
  }
  if (threadIdx.x < SCAN_NB) bsum[threadIdx.x] = s[threadIdx.x] - v;
}

__global__ __launch_bounds__(256) void scan_add_kernel(
    int* __restrict__ row_ptr, const int* __restrict__ bsum,
    int* __restrict__ cursor) {
  const int i = blockIdx.x * 256 + threadIdx.x;
  if (i < N_NODES) {
    const int r = row_ptr[i] + bsum[blockIdx.x];
    row_ptr[i] = r;
    cursor[i] = r;
  }
  if (i == 0) row_ptr[N_NODES] = N_EDGES;
}

// ---------------------------------------------------------------------------
// Fill: permute edges into dst-sorted order, packing (src, weight_bits).
// ---------------------------------------------------------------------------
__global__ __launch_bounds__(256) void fill_kernel(
    const int* __restrict__ esrc, const int* __restrict__ edst,
    const float* __restrict__ ew, int* __restrict__ cursor,
    int2* __restrict__ meta) {
  const int e = blockIdx.x * 256 + threadIdx.x;
  if (e >= N_EDGES) return;
  const int d = edst[e];
  const int pos = atomicAdd(&cursor[d], 1);
  meta[pos] = make_int2(esrc[e], __float_as_int(ew[e]));
}

// ---------------------------------------------------------------------------
// Gather1: h1[n] = sum_{e in row n} w_e * xw1[src_e]. One wave per node.
// ---------------------------------------------------------------------------
__global__ __launch_bounds__(256) void gather1_kernel(
    const float* __restrict__ xw1, const int* __restrict__ row_ptr,
    const int2* __restrict__ meta, float* __restrict__ h1) {
  const int node = blockIdx.x * 4 + (threadIdx.x >> 6);
  const int lane = threadIdx.x & 63;
  const int beg = row_ptr[node];
  const int end = row_ptr[node + 1];
  float4 acc = make_float4(0.f, 0.f, 0.f, 0.f);
  for (int j = beg; j < end; ++j) {
    const int2 m = meta[j];
    const float w = __int_as_float(m.y);
    const float4 v = ((const float4*)(xw1 + (size_t)m.x * FILTERS))[lane];
    acc.x = fmaf(w, v.x, acc.x);
    acc.y = fmaf(w, v.y, acc.y);
    acc.z = fmaf(w, v.z, acc.z);
    acc.w = fmaf(w, v.w, acc.w);
  }
  ((float4*)(h1 + (size_t)node * FILTERS))[lane] = acc;
}

// ---------------------------------------------------------------------------
// GEMM2: H2[M,16] = relu(H1[M,256]) @ W2[256,16]. W2 staged in LDS.
// ---------------------------------------------------------------------------
__global__ __launch_bounds__(256) void gemm2_kernel(
    const float* __restrict__ H1, const float* __restrict__ W2,
    float* __restrict__ H2) {
  __shared__ float w2s[FILTERS * NUM_CLASSES];
  const int tid = threadIdx.x;
  for (int i = tid; i < FILTERS * NUM_CLASSES; i += 256) w2s[i] = W2[i];
  __syncthreads();

  const int row = blockIdx.x * 64 + (tid >> 2);
  if (row >= N_NODES) return;
  const int cg = (tid & 3) * 4;

  const float4* hrow = (const float4*)(H1 + (size_t)row * FILTERS);
  float acc[4] = {0.f, 0.f, 0.f, 0.f};
  for (int k4 = 0; k4 < FILTERS / 4; ++k4) {
    float4 hv = hrow[k4];
    float h[4] = {hv.x, hv.y, hv.z, hv.w};
#pragma unroll
    for (int j = 0; j < 4; ++j) {
      float hh = fmaxf(h[j], 0.f);
      const float* wrow = &w2s[(k4 * 4 + j) * NUM_CLASSES + cg];
#pragma unroll
      for (int c = 0; c < 4; ++c) acc[c] = fmaf(hh, wrow[c], acc[c]);
    }
  }
  *(float4*)(H2 + (size_t)row * NUM_CLASSES + cg) =
      make_float4(acc[0], acc[1], acc[2], acc[3]);
}

// ---------------------------------------------------------------------------
// Gather2 + softmax fused.
// ---------------------------------------------------------------------------
__global__ __launch_bounds__(256) void gather2_softmax_kernel(
    const float* __restrict__ h2, const int* __restrict__ row_ptr,
    const int2* __restrict__ meta, float* __restrict__ out) {
  const int g = threadIdx.x >> 4;
  const int c = threadIdx.x & 15;
  const int node = blockIdx.x * 16 + g;
  const int beg = row_ptr[node];
  const int end = row_ptr[node + 1];
  float acc = 0.f;
  for (int j = beg; j < end; ++j) {
    const int2 m = meta[j];
    acc = fmaf(__int_as_float(m.y), h2[(size_t)m.x * NUM_CLASSES + c], acc);
  }
  float mx = acc;
#pragma unroll
  for (int off = 8; off >= 1; off >>= 1) mx = fmaxf(mx, __shfl_xor(mx, off, 16));
  const float e = __expf(acc - mx);
  float s = e;
#pragma unroll
  for (int off = 8; off >= 1; off >>= 1) s += __shfl_xor(s, off, 16);
  out[(size_t)node * NUM_CLASSES + c] = e / s;
}

extern "C" void kernel_launch(void* const* d_in, const int* in_sizes, int n_in,
                              void* d_out, int out_size, void* d_ws,
                              size_t ws_size, hipStream_t stream) {
  const float* x = (const float*)d_in[0];
  const float* W1 = (const float*)d_in[1];
  const float* W2 = (const float*)d_in[2];
  const float* ew = (const float*)d_in[3];
  const int* esrc = (const int*)d_in[4];
  const int* edst = (const int*)d_in[5];
  float* out = (float*)d_out;

  float* xw1 = (float*)d_ws;                                  // 12.8M f32
  float* h1 = xw1 + (size_t)N_NODES * FILTERS;                // 12.8M f32
  float* h2 = h1 + (size_t)N_NODES * FILTERS;                 // 0.8M f32
  int* row_ptr = (int*)(h2 + (size_t)N_NODES * NUM_CLASSES);  // 50001
  int* cursor = row_ptr + (N_NODES + 1);                      // 50000
  int* deg = cursor + N_NODES;                                // 50000
  int2* meta = (int2*)(((uintptr_t)(deg + N_NODES) + 15) & ~(uintptr_t)15);
  __bf16* w1th = (__bf16*)(meta + N_EDGES);                   // 131072 bf16
  __bf16* w1tl = w1th + D_FEAT * FILTERS;                     // 131072 bf16
  int* bsum = (int*)(w1tl + D_FEAT * FILTERS);                // 196 ints

  // --- CSR build (dst-sorted) ---
  hipMemsetAsync(deg, 0, N_NODES * sizeof(int), stream);
  hist_kernel<<<(N_EDGES + 255) / 256, 256, 0, stream>>>(edst, deg);
  scan_blocks_kernel<<<SCAN_NB, 256, 0, stream>>>(deg, row_ptr, bsum);
  scan_sums_kernel<<<1, 256, 0, stream>>>(bsum);
  scan_add_kernel<<<SCAN_NB, 256, 0, stream>>>(row_ptr, bsum, cursor);
  fill_kernel<<<(N_EDGES + 255) / 256, 256, 0, stream>>>(esrc, edst, ew,
                                                         cursor, meta);

  // --- Layer 1 ---
  split_w1_kernel<<<(D_FEAT * FILTERS) / 256, 256, 0, stream>>>(W1, w1th, w1tl);
  dim3 g1((N_NODES + 127) / 128, FILTERS / 128);
  gemm1_mfma_kernel<<<g1, 256, 0, stream>>>(x, w1th, w1tl, xw1);
  gather1_kernel<<<N_NODES / 4, 256, 0, stream>>>(xw1, row_ptr, meta, h1);

  // --- Layer 2 ---
  gemm2_kernel<<<(N_NODES + 63) / 64, 256, 0, stream>>>(h1, W2, h2);
  gather2_softmax_kernel<<<N_NODES / 16, 256, 0, stream>>>(h2, row_ptr, meta,
                                                           out);
}